// Round 1
// baseline (326.953 us; speedup 1.0000x reference)
//
#include <hip/hip_runtime.h>
#include <hip/hip_bf16.h>

// Sizes fixed by the problem.
#define B_ 2
#define N_ 8192
#define C_ 256
#define H_ 8
#define CH_ 2048  // C_*H_

static constexpr float EPS = 1e-5f;

// ---------------------------------------------------------------------------
// Algebra: with G = emb^T emb  (per batch, 256x256):
//   attn_raw[b,h] = Wq_h^T G[b] Wk_h
//   softmax(instnorm(attn_raw)) = softmax(attn_raw * rsqrt(var+eps))   (mean shift cancels)
//   out[b] = emb[b] @ P[b],  P[b] = sum_h (Wv_h attn_h^T) Wo_h
// Everything between the two emb passes is 256x256 / 256x2048 GEMMs.
//
// ws layout (floats):
//   G    : [B][C][C]       off 0         sz 131072
//   A1t/M: off 131072      sz 1048576    (A1t = G@Wq [B][C][CH]; reused for M [B*H][C][C])
//   attn : [B*H][C][C]     off 1179648   sz 1048576
//   P    : [B][C][C]       off 2228224   sz 131072
// total 2359296 floats = 9.4 MB
// ---------------------------------------------------------------------------

// XOR swizzle for transposed (k-major) operand staging: element (k,m) of a
// 64x64 tile stored at row k, float4-group (m>>2)^(k&15), keeps ds_read_b128
// reads conflict-free and 16B-aligned (no pad needed).
__device__ __forceinline__ int swz(int k, int m) {
    return (k << 6) + ((((m >> 2) ^ (k & 15)) << 2) | (m & 3));
}

// Load 64x64 tile, source already k-major: dst[k][c] = src[(r0+k)*ld + c0+c]
__device__ __forceinline__ void load_tile(float* __restrict__ dst, const float* __restrict__ src,
                                          int r0, int c0, int ld) {
    int t = threadIdx.x;
#pragma unroll
    for (int i = 0; i < 16; ++i) {
        int idx = t + i * 256;
        int r = idx >> 6, c = idx & 63;
        dst[(r << 6) + c] = src[(r0 + r) * ld + c0 + c];
    }
}

// Load 64x64 tile from row-major [m][k] source (k contiguous), store transposed
// + swizzled so compute can read float4 along m.
__device__ __forceinline__ void load_tile_tr(float* __restrict__ dst, const float* __restrict__ src,
                                             int m0, int k0, int ld) {
    int t = threadIdx.x;
#pragma unroll
    for (int i = 0; i < 16; ++i) {
        int idx = t + i * 256;
        int m = idx >> 6, k = idx & 63;
        dst[swz(k, m)] = src[(m0 + m) * ld + k0 + k];
    }
}

template <bool ASWZ, bool BSWZ>
__device__ __forceinline__ void mma64(const float* __restrict__ As, const float* __restrict__ Bs,
                                      float acc[4][4]) {
    int tx = threadIdx.x & 15, ty = threadIdx.x >> 4;
#pragma unroll 8
    for (int kk = 0; kk < 64; ++kk) {
        int ga = ASWZ ? ((ty ^ (kk & 15)) << 2) : (ty << 2);
        int gb = BSWZ ? ((tx ^ (kk & 15)) << 2) : (tx << 2);
        float4 a = *(const float4*)(As + (kk << 6) + ga);
        float4 b = *(const float4*)(Bs + (kk << 6) + gb);
        acc[0][0] = fmaf(a.x, b.x, acc[0][0]); acc[0][1] = fmaf(a.x, b.y, acc[0][1]);
        acc[0][2] = fmaf(a.x, b.z, acc[0][2]); acc[0][3] = fmaf(a.x, b.w, acc[0][3]);
        acc[1][0] = fmaf(a.y, b.x, acc[1][0]); acc[1][1] = fmaf(a.y, b.y, acc[1][1]);
        acc[1][2] = fmaf(a.y, b.z, acc[1][2]); acc[1][3] = fmaf(a.y, b.w, acc[1][3]);
        acc[2][0] = fmaf(a.z, b.x, acc[2][0]); acc[2][1] = fmaf(a.z, b.y, acc[2][1]);
        acc[2][2] = fmaf(a.z, b.z, acc[2][2]); acc[2][3] = fmaf(a.z, b.w, acc[2][3]);
        acc[3][0] = fmaf(a.w, b.x, acc[3][0]); acc[3][1] = fmaf(a.w, b.y, acc[3][1]);
        acc[3][2] = fmaf(a.w, b.z, acc[3][2]); acc[3][3] = fmaf(a.w, b.w, acc[3][3]);
    }
}

__device__ __forceinline__ void store_acc(float* __restrict__ dst, int ld, int r0, int c0,
                                          const float acc[4][4]) {
    int tx = threadIdx.x & 15, ty = threadIdx.x >> 4;
#pragma unroll
    for (int i = 0; i < 4; ++i) {
        float4 v = {acc[i][0], acc[i][1], acc[i][2], acc[i][3]};
        *(float4*)(dst + (r0 + ty * 4 + i) * ld + c0 + tx * 4) = v;
    }
}

// ---------------------------------------------------------------------------

__global__ __launch_bounds__(256) void k_zero(float* __restrict__ G, float* __restrict__ P) {
    int i = blockIdx.x * 256 + threadIdx.x;  // grid 512 -> covers 131072
    G[i] = 0.f;
    P[i] = 0.f;
}

// G[b] = emb[b]^T emb[b], split-K over N with atomics. grid (16 tiles, 16 kchunks, B)
__global__ __launch_bounds__(256) void k_gram(const float* __restrict__ emb, float* __restrict__ G) {
    __shared__ float As[4096], Bs[4096];
    int tile = blockIdx.x, kchunk = blockIdx.y, b = blockIdx.z;
    int c1 = (tile >> 2) * 64, c2 = (tile & 3) * 64;
    const float* E = emb + b * (N_ * C_);
    float acc[4][4] = {};
    for (int kb = 0; kb < 8; ++kb) {
        int n0 = kchunk * 512 + kb * 64;
        load_tile(As, E, n0, c1, C_);  // k-major naturally (k = n)
        load_tile(Bs, E, n0, c2, C_);
        __syncthreads();
        mma64<false, false>(As, Bs, acc);
        __syncthreads();
    }
    float* Gb = G + b * (C_ * C_);
    int tx = threadIdx.x & 15, ty = threadIdx.x >> 4;
#pragma unroll
    for (int i = 0; i < 4; ++i)
#pragma unroll
        for (int j = 0; j < 4; ++j)
            atomicAdd(&Gb[(c1 + ty * 4 + i) * C_ + c2 + tx * 4 + j], acc[i][j]);
}

// A1t[b] = G[b] @ Wq   ([C x CH]); uses G symmetry so A operand is k-major.
// grid (32 jtiles, 4 ctiles, B)
__global__ __launch_bounds__(256) void k_gwq(const float* __restrict__ G, const float* __restrict__ Wq,
                                             float* __restrict__ A1t) {
    __shared__ float As[4096], Bs[4096];
    int jt = blockIdx.x, ct = blockIdx.y, b = blockIdx.z;
    const float* Gb = G + b * (C_ * C_);
    float acc[4][4] = {};
    for (int kb = 0; kb < 4; ++kb) {
        load_tile(As, Gb, kb * 64, ct * 64, C_);   // G[k][c] == G[c][k]
        load_tile(Bs, Wq, kb * 64, jt * 64, CH_);
        __syncthreads();
        mma64<false, false>(As, Bs, acc);
        __syncthreads();
    }
    store_acc(A1t + b * (C_ * CH_), CH_, ct * 64, jt * 64, acc);
}

// attn[b,h] = (Wq_h^T G) @ Wk_h = A1t[:, h*256+d]^T-view @ Wk_h. grid (16 tiles, 16 bh)
__global__ __launch_bounds__(256) void k_attn(const float* __restrict__ A1t, const float* __restrict__ Wk,
                                              float* __restrict__ attn) {
    __shared__ float As[4096], Bs[4096];
    int tile = blockIdx.x, bh = blockIdx.y;
    int b = bh >> 3, h = bh & 7;
    int d0 = (tile >> 2) * 64, e0 = (tile & 3) * 64;
    const float* A = A1t + b * (C_ * CH_);
    float acc[4][4] = {};
    for (int kb = 0; kb < 4; ++kb) {
        load_tile(As, A, kb * 64, h * 256 + d0, CH_);   // As[k=c][d]
        load_tile(Bs, Wk, kb * 64, h * 256 + e0, CH_);  // Bs[k=c][e]
        __syncthreads();
        mma64<false, false>(As, Bs, acc);
        __syncthreads();
    }
    store_acc(attn + bh * (C_ * C_), C_, d0, e0, acc);
}

// Fused variance + softmax (mean shift cancels inside softmax). In-place. grid (16)
__global__ __launch_bounds__(256) void k_sm(float* __restrict__ attn) {
    float* A = attn + blockIdx.x * (C_ * C_);
    int t = threadIdx.x;
    float s = 0.f, ss = 0.f;
    for (int i = t; i < 16384; i += 256) {
        float4 v = ((const float4*)A)[i];
        s += v.x + v.y + v.z + v.w;
        ss += v.x * v.x + v.y * v.y + v.z * v.z + v.w * v.w;
    }
#pragma unroll
    for (int o = 32; o > 0; o >>= 1) { s += __shfl_down(s, o); ss += __shfl_down(ss, o); }
    __shared__ float red[8];
    __shared__ float rs_sh;
    int wid = t >> 6, lane = t & 63;
    if (lane == 0) { red[wid] = s; red[4 + wid] = ss; }
    __syncthreads();
    if (t == 0) {
        float S = red[0] + red[1] + red[2] + red[3];
        float SS = red[4] + red[5] + red[6] + red[7];
        float mu = S * (1.f / 65536.f);
        float var = SS * (1.f / 65536.f) - mu * mu;
        rs_sh = rsqrtf(var + EPS);
    }
    __syncthreads();
    float rs = rs_sh;
    for (int r = wid; r < 256; r += 4) {
        float4 v = ((const float4*)(A + r * 256))[lane];
        v.x *= rs; v.y *= rs; v.z *= rs; v.w *= rs;
        float mx = fmaxf(fmaxf(v.x, v.y), fmaxf(v.z, v.w));
#pragma unroll
        for (int o = 32; o > 0; o >>= 1) mx = fmaxf(mx, __shfl_xor(mx, o));
        float e0 = __expf(v.x - mx), e1 = __expf(v.y - mx), e2 = __expf(v.z - mx), e3 = __expf(v.w - mx);
        float se = e0 + e1 + e2 + e3;
#pragma unroll
        for (int o = 32; o > 0; o >>= 1) se += __shfl_xor(se, o);
        float inv = 1.f / se;
        float4 o4 = {e0 * inv, e1 * inv, e2 * inv, e3 * inv};
        ((float4*)(A + r * 256))[lane] = o4;
    }
}

// M[b,h][c][d] = sum_e Wv[c][h*256+e] * attn[d][e].  grid (16 tiles, 16 bh)
__global__ __launch_bounds__(256) void k_m(const float* __restrict__ attn, const float* __restrict__ Wv,
                                           float* __restrict__ M) {
    __shared__ float As[4096], Bs[4096];
    int tile = blockIdx.x, bh = blockIdx.y;
    int h = bh & 7;
    int c0 = (tile >> 2) * 64, d0 = (tile & 3) * 64;
    const float* At = attn + bh * (C_ * C_);
    float acc[4][4] = {};
    for (int kb = 0; kb < 4; ++kb) {
        load_tile_tr(As, Wv, c0, h * 256 + kb * 64, CH_);  // Ast[e][c] swz
        load_tile_tr(Bs, At, d0, kb * 64, C_);             // Bst[e][d] swz
        __syncthreads();
        mma64<true, true>(As, Bs, acc);
        __syncthreads();
    }
    store_acc(M + bh * (C_ * C_), C_, c0, d0, acc);
}

// P[b] += M[b,h] @ Wo_h  (atomics over h). grid (16 tiles, 16 bh)
__global__ __launch_bounds__(256) void k_p(const float* __restrict__ M, const float* __restrict__ Wo,
                                           float* __restrict__ P) {
    __shared__ float As[4096], Bs[4096];
    int tile = blockIdx.x, bh = blockIdx.y;
    int b = bh >> 3, h = bh & 7;
    int c0 = (tile >> 2) * 64, j0 = (tile & 3) * 64;
    const float* Mb = M + bh * (C_ * C_);
    float acc[4][4] = {};
    for (int kb = 0; kb < 4; ++kb) {
        load_tile_tr(As, Mb, c0, kb * 64, C_);            // Ast[d][c] swz
        load_tile(Bs, Wo + h * C_, kb * 64, j0, CH_);     // Bs[d][j] = Wo[(d*8+h)*256+j]
        __syncthreads();
        mma64<true, false>(As, Bs, acc);
        __syncthreads();
    }
    float* Pb = P + b * (C_ * C_);
    int tx = threadIdx.x & 15, ty = threadIdx.x >> 4;
#pragma unroll
    for (int i = 0; i < 4; ++i)
#pragma unroll
        for (int j = 0; j < 4; ++j)
            atomicAdd(&Pb[(c0 + ty * 4 + i) * C_ + j0 + tx * 4 + j], acc[i][j]);
}

// out[b] = emb[b] @ P[b].  grid (4 jtiles, 128 ntiles, B)
__global__ __launch_bounds__(256) void k_out(const float* __restrict__ emb, const float* __restrict__ P,
                                             float* __restrict__ out) {
    __shared__ float As[4096], Bs[4096];
    int jt = blockIdx.x, nt = blockIdx.y, b = blockIdx.z;
    const float* E = emb + b * (N_ * C_);
    const float* Pb = P + b * (C_ * C_);
    float acc[4][4] = {};
    for (int kb = 0; kb < 4; ++kb) {
        load_tile_tr(As, E, nt * 64, kb * 64, C_);  // Ast[c][n] swz
        load_tile(Bs, Pb, kb * 64, jt * 64, C_);    // Bs[c][j]
        __syncthreads();
        mma64<true, false>(As, Bs, acc);
        __syncthreads();
    }
    store_acc(out + b * (N_ * C_), C_, nt * 64, jt * 64, acc);
}

// ---------------------------------------------------------------------------

extern "C" void kernel_launch(void* const* d_in, const int* in_sizes, int n_in,
                              void* d_out, int out_size, void* d_ws, size_t ws_size,
                              hipStream_t stream) {
    const float* emb = (const float*)d_in[0];
    const float* Wq  = (const float*)d_in[1];
    const float* Wk  = (const float*)d_in[2];
    const float* Wv  = (const float*)d_in[3];
    const float* Wo  = (const float*)d_in[4];
    float* out = (float*)d_out;
    float* ws  = (float*)d_ws;

    float* G    = ws;             // 131072
    float* A1t  = ws + 131072;    // 1048576 (reused as M)
    float* M    = ws + 131072;    //   A1t dead after k_attn
    float* attn = ws + 1179648;   // 1048576
    float* P    = ws + 2228224;   // 131072  (total 9.4 MB)

    k_zero<<<dim3(512), dim3(256), 0, stream>>>(G, P);
    k_gram<<<dim3(16, 16, B_), dim3(256), 0, stream>>>(emb, G);
    k_gwq<<<dim3(32, 4, B_), dim3(256), 0, stream>>>(G, Wq, A1t);
    k_attn<<<dim3(16, 16), dim3(256), 0, stream>>>(A1t, Wk, attn);
    k_sm<<<dim3(16), dim3(256), 0, stream>>>(attn);
    k_m<<<dim3(16, 16), dim3(256), 0, stream>>>(attn, Wv, M);
    k_p<<<dim3(16, 16), dim3(256), 0, stream>>>(M, Wo, P);
    k_out<<<dim3(4, 128, B_), dim3(256), 0, stream>>>(emb, P, out);
}

// Round 2
// 176.332 us; speedup vs baseline: 1.8542x; 1.8542x over previous
//
#include <hip/hip_runtime.h>
#include <hip/hip_bf16.h>

#define NB 2
#define NN 8192
#define NC 256
#define NH 8
#define NCH 2048

static constexpr float EPS = 1e-5f;

// ---------------------------------------------------------------------------
// Factorization (per batch b, head h, all matrices tiny except emb):
//   G = emb^T emb                        [256x256]   (MFMA, split-K partials)
//   T1[hd][c] = sum_c' Wq[c'][hd] G[c'][c]           (TN GEMM)
//   attn[d][e] = sum_c T1[hd][c] Wk[c][he]           (TN GEMM, + var stats)
//   SM = softmax(attn * rsqrt(var+eps))              (mean shift cancels)
//   M[c][d] = sum_e Wv[c][he] SM[d][e]               (TN GEMM)
//   Pt[j][c] += sum_d Wor[h][j][d] M[c][d]           (TN GEMM, per-h partials)
//   out[n][j] = sum_c emb[n][c] Pt[j][c]             (TN GEMM, fp32-split A)
// All operands bf16 hi/lo pairs: x = hi + lo; acc += hi*hi + hi*lo + lo*hi
// (lo*lo term ~2^-18 relative, dropped). MFMA 16x16x32_bf16.
// ---------------------------------------------------------------------------

typedef __attribute__((ext_vector_type(8))) short bf16x8;
typedef __attribute__((ext_vector_type(4))) float f32x4;

#define MFMA16(a, b, c) __builtin_amdgcn_mfma_f32_16x16x32_bf16(a, b, c, 0, 0, 0)

// ---- ws layout -------------------------------------------------------------
// float region (floats):
//   Gp   [2][16][256][256] @ 0        (2,097,152)  gram split-K partials
//   attn [16][256][256]    @ 0        (alias; Gp dead after k_s2)
//   Ptp  [16][256][256]    @ 1048576  (alias upper half of Gp)
//   stats[64]              @ 2097152
// ushort region starts at float offset 2097216:
static constexpr int ETH  = 0;         // Et hi [2][256][8192]
static constexpr int ETL  = 4194304;
static constexpr int WQTH = 8388608;   // Wq^T hi [2048][256]
static constexpr int WQTL = 8912896;
static constexpr int WKTH = 9437184;
static constexpr int WKTL = 9961472;
static constexpr int WVH  = 10485760;  // Wv hi [256][2048] (untransposed: k=h*256+e contiguous)
static constexpr int WVL  = 11010048;
static constexpr int WORH = 11534336;  // Wor hi [8][256][256]: Wor[h][j][d] = Wo[d*8+h][j]
static constexpr int WORL = 12058624;
static constexpr int GHH  = 12582912;  // G hi [2][256][256]
static constexpr int GHL  = 12713984;
static constexpr int T1H  = 12845056;  // T1 hi [2][2048][256]; reused as M [16][256][256]
static constexpr int T1L  = 13893632;
static constexpr int SMH  = 14942208;  // softmax hi [16][256][256]
static constexpr int SML  = 15990784;
static constexpr int PTH  = 17039360;  // Pt hi [2][256][256]
static constexpr int PTL  = 17170432;

// ---- helpers ---------------------------------------------------------------

__device__ __forceinline__ ushort bf16rn(float x) {
    uint u = __float_as_uint(x);
    return (ushort)((u + 0x7fffu + ((u >> 16) & 1u)) >> 16);
}
__device__ __forceinline__ float bf2f(ushort h) { return __uint_as_float(((uint)h) << 16); }

// stage a 64x64 bf16 tile (k-contiguous source) into XOR-swizzled LDS.
// LDS row = m (128 B); 16B slot s within row holds k-group (s ^ (m&7)).
__device__ __forceinline__ void stage64(ushort* __restrict__ lds, const ushort* __restrict__ src,
                                        int row0, int k0, int ld) {
    int t = threadIdx.x;
    int g = t & 7, r = t >> 3;
#pragma unroll
    for (int i = 0; i < 2; ++i, r += 32) {
        uint4 v = *(const uint4*)(src + (row0 + r) * ld + k0 + g * 8);
        *(uint4*)((char*)lds + r * 128 + ((g ^ (r & 7)) << 4)) = v;
    }
}

// stage 64x64 from fp32 source with on-the-fly hi/lo split (for emb operand)
__device__ __forceinline__ void stage64_f32(ushort* __restrict__ ldsh, ushort* __restrict__ ldsl,
                                            const float* __restrict__ src, int row0, int k0, int ld) {
    int t = threadIdx.x;
    int g = t & 15, r = t >> 4;
#pragma unroll
    for (int i = 0; i < 4; ++i, r += 16) {
        float4 v = *(const float4*)(src + (row0 + r) * ld + k0 + g * 4);
        ushort h0 = bf16rn(v.x), h1 = bf16rn(v.y), h2 = bf16rn(v.z), h3 = bf16rn(v.w);
        ushort e0 = bf16rn(v.x - bf2f(h0)), e1 = bf16rn(v.y - bf2f(h1));
        ushort e2 = bf16rn(v.z - bf2f(h2)), e3 = bf16rn(v.w - bf2f(h3));
        int byte = r * 128 + ((((g >> 1) ^ (r & 7)) << 4) | ((g & 1) << 3));
        ushort4 hv = {h0, h1, h2, h3}, lv = {e0, e1, e2, e3};
        *(ushort4*)((char*)ldsh + byte) = hv;
        *(ushort4*)((char*)ldsl + byte) = lv;
    }
}

// read one A/B fragment: lane holds row rbase+(l&15), 8 bf16 at k = ks*32+(l>>4)*8
__device__ __forceinline__ bf16x8 frag64(const ushort* __restrict__ lds, int rbase, int ks) {
    int l = threadIdx.x & 63;
    int r = rbase + (l & 15);
    int slot = (ks * 4 + (l >> 4)) ^ (r & 7);
    return *(const bf16x8*)((const char*)lds + r * 128 + slot * 16);
}

__device__ __forceinline__ void mfma_tile(const ushort* Ah, const ushort* Al,
                                          const ushort* Bh, const ushort* Bl,
                                          int wm, int wn, f32x4 acc[2][2]) {
#pragma unroll
    for (int ks = 0; ks < 2; ++ks) {
        bf16x8 ah[2], al[2], bh[2], bl[2];
        ah[0] = frag64(Ah, wm, ks);      ah[1] = frag64(Ah, wm + 16, ks);
        al[0] = frag64(Al, wm, ks);      al[1] = frag64(Al, wm + 16, ks);
        bh[0] = frag64(Bh, wn, ks);      bh[1] = frag64(Bh, wn + 16, ks);
        bl[0] = frag64(Bl, wn, ks);      bl[1] = frag64(Bl, wn + 16, ks);
#pragma unroll
        for (int mi = 0; mi < 2; ++mi)
#pragma unroll
            for (int ni = 0; ni < 2; ++ni) {
                acc[mi][ni] = MFMA16(ah[mi], bh[ni], acc[mi][ni]);
                acc[mi][ni] = MFMA16(ah[mi], bl[ni], acc[mi][ni]);
                acc[mi][ni] = MFMA16(al[mi], bh[ni], acc[mi][ni]);
            }
    }
}

// full TN GEMM over nkt 64-wide k-tiles; 4 waves, 64x64 output tile
__device__ __forceinline__ void gemm_core(const ushort* Ahi, const ushort* Alo, int arow0, int lda, int k0a,
                                          const ushort* Bhi, const ushort* Blo, int brow0, int ldb, int k0b,
                                          int nkt, ushort* lds, f32x4 acc[2][2]) {
    ushort* Ah = lds; ushort* Al = lds + 4096; ushort* Bh = lds + 8192; ushort* Bl = lds + 12288;
    int w = threadIdx.x >> 6;
    int wm = (w >> 1) * 32, wn = (w & 1) * 32;
    for (int t = 0; t < nkt; ++t) {
        stage64(Ah, Ahi, arow0, k0a + t * 64, lda);
        stage64(Al, Alo, arow0, k0a + t * 64, lda);
        stage64(Bh, Bhi, brow0, k0b + t * 64, ldb);
        stage64(Bl, Blo, brow0, k0b + t * 64, ldb);
        __syncthreads();
        mfma_tile(Ah, Al, Bh, Bl, wm, wn, acc);
        __syncthreads();
    }
}

__device__ __forceinline__ void ep_hilo(ushort* Dh, ushort* Dl, int ld, int row0, int col0, f32x4 acc[2][2]) {
    int l = threadIdx.x & 63, w = threadIdx.x >> 6;
    int wm = (w >> 1) * 32, wn = (w & 1) * 32;
#pragma unroll
    for (int mi = 0; mi < 2; ++mi)
#pragma unroll
        for (int ni = 0; ni < 2; ++ni)
#pragma unroll
            for (int r = 0; r < 4; ++r) {
                float x = acc[mi][ni][r];
                int idx = (row0 + wm + mi * 16 + (l >> 4) * 4 + r) * ld + col0 + wn + ni * 16 + (l & 15);
                ushort h = bf16rn(x);
                Dh[idx] = h;
                Dl[idx] = bf16rn(x - bf2f(h));
            }
}

__device__ __forceinline__ void ep_f32(float* D, int ld, int row0, int col0, f32x4 acc[2][2]) {
    int l = threadIdx.x & 63, w = threadIdx.x >> 6;
    int wm = (w >> 1) * 32, wn = (w & 1) * 32;
#pragma unroll
    for (int mi = 0; mi < 2; ++mi)
#pragma unroll
        for (int ni = 0; ni < 2; ++ni)
#pragma unroll
            for (int r = 0; r < 4; ++r)
                D[(row0 + wm + mi * 16 + (l >> 4) * 4 + r) * ld + col0 + wn + ni * 16 + (l & 15)] = acc[mi][ni][r];
}

// ---- kernels ---------------------------------------------------------------

// S0: emb -> Et hi/lo [b][c][n] (transpose + split); also zero stats
__global__ __launch_bounds__(256) void k_s0(const float* __restrict__ emb, ushort* __restrict__ us,
                                            float* __restrict__ stats) {
    __shared__ uint lds[64][65];
    int nt = blockIdx.x, ct = blockIdx.y, b = blockIdx.z;
    int t = threadIdx.x;
    if (nt == 0 && ct == 0 && b == 0 && t < 64) stats[t] = 0.f;
    const float* E = emb + b * (NN * NC);
    int n0 = nt * 64, c0 = ct * 64;
    int r = t >> 4, g = t & 15;
#pragma unroll
    for (int i = 0; i < 4; ++i) {
        int n = r + i * 16;
        float4 v = *(const float4*)(E + (n0 + n) * NC + c0 + g * 4);
        ushort h;
        h = bf16rn(v.x); lds[g * 4 + 0][n] = h | ((uint)bf16rn(v.x - bf2f(h)) << 16);
        h = bf16rn(v.y); lds[g * 4 + 1][n] = h | ((uint)bf16rn(v.y - bf2f(h)) << 16);
        h = bf16rn(v.z); lds[g * 4 + 2][n] = h | ((uint)bf16rn(v.z - bf2f(h)) << 16);
        h = bf16rn(v.w); lds[g * 4 + 3][n] = h | ((uint)bf16rn(v.w - bf2f(h)) << 16);
    }
    __syncthreads();
    ushort* EH = us + ETH + b * (NC * NN);
    ushort* EL = us + ETL + b * (NC * NN);
    int c = t >> 3, q = t & 7;
#pragma unroll
    for (int i = 0; i < 2; ++i) {
        int cc = c + i * 32;
        uint a0 = lds[cc][q * 8 + 0], a1 = lds[cc][q * 8 + 1], a2 = lds[cc][q * 8 + 2], a3 = lds[cc][q * 8 + 3];
        uint a4 = lds[cc][q * 8 + 4], a5 = lds[cc][q * 8 + 5], a6 = lds[cc][q * 8 + 6], a7 = lds[cc][q * 8 + 7];
        uint4 hv = {(a0 & 0xffffu) | (a1 << 16), (a2 & 0xffffu) | (a3 << 16),
                    (a4 & 0xffffu) | (a5 << 16), (a6 & 0xffffu) | (a7 << 16)};
        uint4 lv = {(a0 >> 16) | (a1 & 0xffff0000u), (a2 >> 16) | (a3 & 0xffff0000u),
                    (a4 >> 16) | (a5 & 0xffff0000u), (a6 >> 16) | (a7 & 0xffff0000u)};
        *(uint4*)(EH + (c0 + cc) * NN + n0 + q * 8) = hv;
        *(uint4*)(EL + (c0 + cc) * NN + n0 + q * 8) = lv;
    }
}

// S1: Wq/Wk -> transposed hi/lo [2048][256]
__global__ __launch_bounds__(256) void k_s1(const float* __restrict__ wq, const float* __restrict__ wk,
                                            ushort* __restrict__ us) {
    __shared__ uint lds[64][65];
    int jt = blockIdx.x, ct = blockIdx.y, z = blockIdx.z;
    const float* W = z ? wk : wq;
    ushort* DH = us + (z ? WKTH : WQTH);
    ushort* DL = us + (z ? WKTL : WQTL);
    int t = threadIdx.x, j0 = jt * 64, c0 = ct * 64;
    int r = t >> 4, g = t & 15;
#pragma unroll
    for (int i = 0; i < 4; ++i) {
        int c = r + i * 16;
        float4 v = *(const float4*)(W + (c0 + c) * NCH + j0 + g * 4);
        ushort h;
        h = bf16rn(v.x); lds[g * 4 + 0][c] = h | ((uint)bf16rn(v.x - bf2f(h)) << 16);
        h = bf16rn(v.y); lds[g * 4 + 1][c] = h | ((uint)bf16rn(v.y - bf2f(h)) << 16);
        h = bf16rn(v.z); lds[g * 4 + 2][c] = h | ((uint)bf16rn(v.z - bf2f(h)) << 16);
        h = bf16rn(v.w); lds[g * 4 + 3][c] = h | ((uint)bf16rn(v.w - bf2f(h)) << 16);
    }
    __syncthreads();
    int j = t >> 3, q = t & 7;
#pragma unroll
    for (int i = 0; i < 2; ++i) {
        int jj = j + i * 32;
        uint a0 = lds[jj][q * 8 + 0], a1 = lds[jj][q * 8 + 1], a2 = lds[jj][q * 8 + 2], a3 = lds[jj][q * 8 + 3];
        uint a4 = lds[jj][q * 8 + 4], a5 = lds[jj][q * 8 + 5], a6 = lds[jj][q * 8 + 6], a7 = lds[jj][q * 8 + 7];
        uint4 hv = {(a0 & 0xffffu) | (a1 << 16), (a2 & 0xffffu) | (a3 << 16),
                    (a4 & 0xffffu) | (a5 << 16), (a6 & 0xffffu) | (a7 << 16)};
        uint4 lv = {(a0 >> 16) | (a1 & 0xffff0000u), (a2 >> 16) | (a3 & 0xffff0000u),
                    (a4 >> 16) | (a5 & 0xffff0000u), (a6 >> 16) | (a7 & 0xffff0000u)};
        *(uint4*)(DH + (j0 + jj) * NC + c0 + q * 8) = hv;
        *(uint4*)(DL + (j0 + jj) * NC + c0 + q * 8) = lv;
    }
}

// S1b: Wo -> Wor hi/lo [h][j][d]  (Wor[h][j][d] = Wo[d*8+h][j])
__global__ __launch_bounds__(256) void k_s1b(const float* __restrict__ wo, ushort* __restrict__ us) {
    __shared__ uint lds[64][65];
    int jt = blockIdx.x, dt = blockIdx.y, h = blockIdx.z;
    int t = threadIdx.x, j0 = jt * 64, d0 = dt * 64;
    int r = t >> 4, g = t & 15;
#pragma unroll
    for (int i = 0; i < 4; ++i) {
        int d = r + i * 16;
        float4 v = *(const float4*)(wo + ((d0 + d) * 8 + h) * NC + j0 + g * 4);
        ushort hh;
        hh = bf16rn(v.x); lds[g * 4 + 0][d] = hh | ((uint)bf16rn(v.x - bf2f(hh)) << 16);
        hh = bf16rn(v.y); lds[g * 4 + 1][d] = hh | ((uint)bf16rn(v.y - bf2f(hh)) << 16);
        hh = bf16rn(v.z); lds[g * 4 + 2][d] = hh | ((uint)bf16rn(v.z - bf2f(hh)) << 16);
        hh = bf16rn(v.w); lds[g * 4 + 3][d] = hh | ((uint)bf16rn(v.w - bf2f(hh)) << 16);
    }
    __syncthreads();
    int j = t >> 3, q = t & 7;
#pragma unroll
    for (int i = 0; i < 2; ++i) {
        int jj = j + i * 32;
        uint a0 = lds[jj][q * 8 + 0], a1 = lds[jj][q * 8 + 1], a2 = lds[jj][q * 8 + 2], a3 = lds[jj][q * 8 + 3];
        uint a4 = lds[jj][q * 8 + 4], a5 = lds[jj][q * 8 + 5], a6 = lds[jj][q * 8 + 6], a7 = lds[jj][q * 8 + 7];
        uint4 hv = {(a0 & 0xffffu) | (a1 << 16), (a2 & 0xffffu) | (a3 << 16),
                    (a4 & 0xffffu) | (a5 << 16), (a6 & 0xffffu) | (a7 << 16)};
        uint4 lv = {(a0 >> 16) | (a1 & 0xffff0000u), (a2 >> 16) | (a3 & 0xffff0000u),
                    (a4 >> 16) | (a5 & 0xffff0000u), (a6 >> 16) | (a7 & 0xffff0000u)};
        *(uint4*)(us + WORH + h * 65536 + (j0 + jj) * NC + d0 + q * 8) = hv;
        *(uint4*)(us + WORL + h * 65536 + (j0 + jj) * NC + d0 + q * 8) = lv;
    }
}

// plain split (Wv): [256][2048] fp32 -> hi/lo bf16 same layout
__global__ __launch_bounds__(256) void k_splitv(const float* __restrict__ wv, ushort* __restrict__ us) {
    int i = (blockIdx.x * 256 + threadIdx.x) * 4;
    float4 v = *(const float4*)(wv + i);
    ushort h0 = bf16rn(v.x), h1 = bf16rn(v.y), h2 = bf16rn(v.z), h3 = bf16rn(v.w);
    ushort e0 = bf16rn(v.x - bf2f(h0)), e1 = bf16rn(v.y - bf2f(h1));
    ushort e2 = bf16rn(v.z - bf2f(h2)), e3 = bf16rn(v.w - bf2f(h3));
    ushort4 hv = {h0, h1, h2, h3}, lv = {e0, e1, e2, e3};
    *(ushort4*)(us + WVH + i) = hv;
    *(ushort4*)(us + WVL + i) = lv;
}

// G1: gram split-K partials. grid (16 tiles, 16 kc, 2 b)
__global__ __launch_bounds__(256) void k_gram(const ushort* __restrict__ us, float* __restrict__ gp) {
    __shared__ ushort lds[16384];
    int tile = blockIdx.x, kc = blockIdx.y, b = blockIdx.z;
    int c1 = (tile >> 2) * 64, c2 = (tile & 3) * 64;
    const ushort* eh = us + ETH + b * (NC * NN);
    const ushort* el = us + ETL + b * (NC * NN);
    f32x4 acc[2][2] = {{{0.f, 0.f, 0.f, 0.f}, {0.f, 0.f, 0.f, 0.f}},
                       {{0.f, 0.f, 0.f, 0.f}, {0.f, 0.f, 0.f, 0.f}}};
    gemm_core(eh, el, c1, NN, kc * 512, eh, el, c2, NN, kc * 512, 8, lds, acc);
    ep_f32(gp + (b * 16 + kc) * 65536, NC, c1, c2, acc);
}

// S2: sum 16 gram partials, split -> Ghi/Glo. grid (64, 2)
__global__ __launch_bounds__(256) void k_s2(const float* __restrict__ gp, ushort* __restrict__ us) {
    int b = blockIdx.y;
    int i = (blockIdx.x * 256 + threadIdx.x) * 4;
    const float* src = gp + b * 16 * 65536 + i;
    float4 s = {0.f, 0.f, 0.f, 0.f};
#pragma unroll
    for (int kc = 0; kc < 16; ++kc) {
        float4 v = *(const float4*)(src + kc * 65536);
        s.x += v.x; s.y += v.y; s.z += v.z; s.w += v.w;
    }
    ushort h0 = bf16rn(s.x), h1 = bf16rn(s.y), h2 = bf16rn(s.z), h3 = bf16rn(s.w);
    ushort e0 = bf16rn(s.x - bf2f(h0)), e1 = bf16rn(s.y - bf2f(h1));
    ushort e2 = bf16rn(s.z - bf2f(h2)), e3 = bf16rn(s.w - bf2f(h3));
    ushort4 hv = {h0, h1, h2, h3}, lv = {e0, e1, e2, e3};
    *(ushort4*)(us + GHH + b * 65536 + i) = hv;
    *(ushort4*)(us + GHL + b * 65536 + i) = lv;
}

// G2: T1 = Wq^T G. grid (32 mt, 4 nt, 2 b)
__global__ __launch_bounds__(256) void k_t1(ushort* __restrict__ us) {
    __shared__ ushort lds[16384];
    int mt = blockIdx.x, nt = blockIdx.y, b = blockIdx.z;
    f32x4 acc[2][2] = {{{0.f, 0.f, 0.f, 0.f}, {0.f, 0.f, 0.f, 0.f}},
                       {{0.f, 0.f, 0.f, 0.f}, {0.f, 0.f, 0.f, 0.f}}};
    gemm_core(us + WQTH, us + WQTL, mt * 64, NC, 0,
              us + GHH + b * 65536, us + GHL + b * 65536, nt * 64, NC, 0, 4, lds, acc);
    ep_hilo(us + T1H + b * 524288, us + T1L + b * 524288, NC, mt * 64, nt * 64, acc);
}

// G3: attn = T1 @ Wk (per head) + variance stats. grid (16 tiles, 16 bh)
__global__ __launch_bounds__(256) void k_attn(ushort* __restrict__ us, float* __restrict__ attn,
                                              float* __restrict__ stats) {
    __shared__ ushort lds[16384];
    int tile = blockIdx.x, bh = blockIdx.y;
    int b = bh >> 3, h = bh & 7;
    int row0 = (tile >> 2) * 64, col0 = (tile & 3) * 64;
    f32x4 acc[2][2] = {{{0.f, 0.f, 0.f, 0.f}, {0.f, 0.f, 0.f, 0.f}},
                       {{0.f, 0.f, 0.f, 0.f}, {0.f, 0.f, 0.f, 0.f}}};
    gemm_core(us + T1H + b * 524288, us + T1L + b * 524288, h * 256 + row0, NC, 0,
              us + WKTH, us + WKTL, h * 256 + col0, NC, 0, 4, lds, acc);
    float* D = attn + bh * 65536;
    int l = threadIdx.x & 63, w = threadIdx.x >> 6;
    int wm = (w >> 1) * 32, wn = (w & 1) * 32;
    float lsum = 0.f, lss = 0.f;
#pragma unroll
    for (int mi = 0; mi < 2; ++mi)
#pragma unroll
        for (int ni = 0; ni < 2; ++ni)
#pragma unroll
            for (int r = 0; r < 4; ++r) {
                float x = acc[mi][ni][r];
                D[(row0 + wm + mi * 16 + (l >> 4) * 4 + r) * NC + col0 + wn + ni * 16 + (l & 15)] = x;
                lsum += x; lss += x * x;
            }
#pragma unroll
    for (int o = 32; o > 0; o >>= 1) { lsum += __shfl_xor(lsum, o); lss += __shfl_xor(lss, o); }
    if (l == 0) { atomicAdd(&stats[bh * 2], lsum); atomicAdd(&stats[bh * 2 + 1], lss); }
}

// S3: fused instnorm-scale + softmax, write hi/lo. grid (16 bh, 4 rb)
__global__ __launch_bounds__(256) void k_sm(const float* __restrict__ attn, const float* __restrict__ stats,
                                            ushort* __restrict__ us) {
    int bh = blockIdx.x, rb = blockIdx.y;
    float mean = stats[bh * 2] * (1.f / 65536.f);
    float var = stats[bh * 2 + 1] * (1.f / 65536.f) - mean * mean;
    float rs = rsqrtf(var + EPS);
    int w = threadIdx.x >> 6, l = threadIdx.x & 63;
    const float* src = attn + bh * 65536;
    ushort* dh = us + SMH + bh * 65536;
    ushort* dl = us + SML + bh * 65536;
    for (int rr = 0; rr < 16; ++rr) {
        int row = rb * 64 + w * 16 + rr;
        float4 v = *(const float4*)(src + row * 256 + l * 4);
        v.x *= rs; v.y *= rs; v.z *= rs; v.w *= rs;
        float mx = fmaxf(fmaxf(v.x, v.y), fmaxf(v.z, v.w));
#pragma unroll
        for (int o = 32; o > 0; o >>= 1) mx = fmaxf(mx, __shfl_xor(mx, o));
        float e0 = __expf(v.x - mx), e1 = __expf(v.y - mx), e2 = __expf(v.z - mx), e3 = __expf(v.w - mx);
        float se = e0 + e1 + e2 + e3;
#pragma unroll
        for (int o = 32; o > 0; o >>= 1) se += __shfl_xor(se, o);
        float inv = 1.f / se;
        e0 *= inv; e1 *= inv; e2 *= inv; e3 *= inv;
        ushort h0 = bf16rn(e0), h1 = bf16rn(e1), h2 = bf16rn(e2), h3 = bf16rn(e3);
        ushort f0 = bf16rn(e0 - bf2f(h0)), f1 = bf16rn(e1 - bf2f(h1));
        ushort f2 = bf16rn(e2 - bf2f(h2)), f3 = bf16rn(e3 - bf2f(h3));
        ushort4 hv = {h0, h1, h2, h3}, lv = {f0, f1, f2, f3};
        *(ushort4*)(dh + row * 256 + l * 4) = hv;
        *(ushort4*)(dl + row * 256 + l * 4) = lv;
    }
}

// G5: M[c][d] = sum_e Wv[c][h*256+e] SM[d][e]. grid (16 tiles, 16 bh). M overwrites T1.
__global__ __launch_bounds__(256) void k_m(ushort* __restrict__ us) {
    __shared__ ushort lds[16384];
    int tile = blockIdx.x, bh = blockIdx.y;
    int h = bh & 7;
    int c0 = (tile >> 2) * 64, d0 = (tile & 3) * 64;
    f32x4 acc[2][2] = {{{0.f, 0.f, 0.f, 0.f}, {0.f, 0.f, 0.f, 0.f}},
                       {{0.f, 0.f, 0.f, 0.f}, {0.f, 0.f, 0.f, 0.f}}};
    gemm_core(us + WVH, us + WVL, c0, NCH, h * 256,
              us + SMH + bh * 65536, us + SML + bh * 65536, d0, NC, 0, 4, lds, acc);
    ep_hilo(us + T1H + bh * 65536, us + T1L + bh * 65536, NC, c0, d0, acc);
}

// G6: Ptp[bh][j][c] = sum_d Wor[h][j][d] M[bh][c][d]. grid (16 tiles, 16 bh)
__global__ __launch_bounds__(256) void k_pt(ushort* __restrict__ us, float* __restrict__ ptp) {
    __shared__ ushort lds[16384];
    int tile = blockIdx.x, bh = blockIdx.y;
    int h = bh & 7;
    int j0 = (tile >> 2) * 64, c0 = (tile & 3) * 64;
    f32x4 acc[2][2] = {{{0.f, 0.f, 0.f, 0.f}, {0.f, 0.f, 0.f, 0.f}},
                       {{0.f, 0.f, 0.f, 0.f}, {0.f, 0.f, 0.f, 0.f}}};
    gemm_core(us + WORH + h * 65536, us + WORL + h * 65536, j0, NC, 0,
              us + T1H + bh * 65536, us + T1L + bh * 65536, c0, NC, 0, 4, lds, acc);
    ep_f32(ptp + bh * 65536, NC, j0, c0, acc);
}

// S4: Pt[b] = sum_h Ptp[b*8+h], split -> hi/lo. grid (64, 2)
__global__ __launch_bounds__(256) void k_s4(const float* __restrict__ ptp, ushort* __restrict__ us) {
    int b = blockIdx.y;
    int i = (blockIdx.x * 256 + threadIdx.x) * 4;
    const float* src = ptp + b * 8 * 65536 + i;
    float4 s = {0.f, 0.f, 0.f, 0.f};
#pragma unroll
    for (int h = 0; h < 8; ++h) {
        float4 v = *(const float4*)(src + h * 65536);
        s.x += v.x; s.y += v.y; s.z += v.z; s.w += v.w;
    }
    ushort h0 = bf16rn(s.x), h1 = bf16rn(s.y), h2 = bf16rn(s.z), h3 = bf16rn(s.w);
    ushort e0 = bf16rn(s.x - bf2f(h0)), e1 = bf16rn(s.y - bf2f(h1));
    ushort e2 = bf16rn(s.z - bf2f(h2)), e3 = bf16rn(s.w - bf2f(h3));
    ushort4 hv = {h0, h1, h2, h3}, lv = {e0, e1, e2, e3};
    *(ushort4*)(us + PTH + b * 65536 + i) = hv;
    *(ushort4*)(us + PTL + b * 65536 + i) = lv;
}

// G7: out = emb @ Pt^T. grid (128 nt, 4 jt, 2 b). A split on the fly from fp32.
__global__ __launch_bounds__(256) void k_out(const float* __restrict__ emb, const ushort* __restrict__ us,
                                             float* __restrict__ out) {
    __shared__ ushort lds[16384];
    ushort* Ah = lds; ushort* Al = lds + 4096; ushort* Bh = lds + 8192; ushort* Bl = lds + 12288;
    int nt = blockIdx.x, jt = blockIdx.y, b = blockIdx.z;
    const float* E = emb + b * (NN * NC);
    const ushort* PH = us + PTH + b * 65536;
    const ushort* PL = us + PTL + b * 65536;
    int w = threadIdx.x >> 6;
    int wm = (w >> 1) * 32, wn = (w & 1) * 32;
    f32x4 acc[2][2] = {{{0.f, 0.f, 0.f, 0.f}, {0.f, 0.f, 0.f, 0.f}},
                       {{0.f, 0.f, 0.f, 0.f}, {0.f, 0.f, 0.f, 0.f}}};
    for (int t = 0; t < 4; ++t) {
        stage64_f32(Ah, Al, E, nt * 64, t * 64, NC);
        stage64(Bh, PH, jt * 64, t * 64, NC);
        stage64(Bl, PL, jt * 64, t * 64, NC);
        __syncthreads();
        mfma_tile(Ah, Al, Bh, Bl, wm, wn, acc);
        __syncthreads();
    }
    ep_f32(out + b * (NN * NC), NC, nt * 64, jt * 64, acc);
}

// ---------------------------------------------------------------------------

extern "C" void kernel_launch(void* const* d_in, const int* in_sizes, int n_in,
                              void* d_out, int out_size, void* d_ws, size_t ws_size,
                              hipStream_t stream) {
    const float* emb = (const float*)d_in[0];
    const float* Wq  = (const float*)d_in[1];
    const float* Wk  = (const float*)d_in[2];
    const float* Wv  = (const float*)d_in[3];
    const float* Wo  = (const float*)d_in[4];
    float* out = (float*)d_out;
    float* ws  = (float*)d_ws;

    float* Gp    = ws;                 // [2][16][256][256]
    float* attn  = ws;                 // alias (Gp dead after k_s2)
    float* Ptp   = ws + 1048576;       // alias upper half
    float* stats = ws + 2097152;       // 64 floats
    ushort* us   = (ushort*)(ws + 2097216);

    k_s0    <<<dim3(128, 4, NB), dim3(256), 0, stream>>>(emb, us, stats);
    k_s1    <<<dim3(32, 4, 2),   dim3(256), 0, stream>>>(Wq, Wk, us);
    k_s1b   <<<dim3(4, 4, 8),    dim3(256), 0, stream>>>(Wo, us);
    k_splitv<<<dim3(512),        dim3(256), 0, stream>>>(Wv, us);
    k_gram  <<<dim3(16, 16, NB), dim3(256), 0, stream>>>(us, Gp);
    k_s2    <<<dim3(64, NB),     dim3(256), 0, stream>>>(Gp, us);
    k_t1    <<<dim3(32, 4, NB),  dim3(256), 0, stream>>>(us);
    k_attn  <<<dim3(16, 16),     dim3(256), 0, stream>>>(us, attn, stats);
    k_sm    <<<dim3(16, 4),      dim3(256), 0, stream>>>(attn, stats, us);
    k_m     <<<dim3(16, 16),     dim3(256), 0, stream>>>(us);
    k_pt    <<<dim3(16, 16),     dim3(256), 0, stream>>>(us, Ptp);
    k_s4    <<<dim3(64, NB),     dim3(256), 0, stream>>>(Ptp, us);
    k_out   <<<dim3(128, 4, NB), dim3(256), 0, stream>>>(emb, us, out);
}